// Round 6
// baseline (2548.810 us; speedup 1.0000x reference)
//
#include <hip/hip_runtime.h>
#include <math.h>

#define NPROD 50
#define DXF 32
#define DZF 20
#define WUW 128
#define LXD 16
#define LZD 16

typedef __attribute__((ext_vector_type(8))) short short8;
typedef __attribute__((ext_vector_type(4))) float float4_;

__device__ __forceinline__ short f2bf(float x) {
    unsigned u = __builtin_bit_cast(unsigned, x);
    u += 0x7fffu + ((u >> 16) & 1u);
    return (short)(u >> 16);
}
__device__ __forceinline__ unsigned pkbf(float a, float b) {
#if __has_builtin(__builtin_amdgcn_cvt_pk_bf16_f32)
    auto v = __builtin_amdgcn_cvt_pk_bf16_f32(a, b);
    return __builtin_bit_cast(unsigned, v);
#else
    return (unsigned)(unsigned short)f2bf(a) | ((unsigned)(unsigned short)f2bf(b) << 16);
#endif
}
// elu(x) = med3(x, exp2(x*log2e)-1, 0)
__device__ __forceinline__ float elu_med3(float x) {
    float e = __builtin_amdgcn_exp2f(x * 1.44269504089f) - 1.0f;
#if __has_builtin(__builtin_amdgcn_fmed3f)
    return __builtin_amdgcn_fmed3f(x, e, 0.0f);
#else
    return x > 0.0f ? x : e;
#endif
}
__device__ __forceinline__ float elu_fast(float x) {
    float e = __builtin_amdgcn_exp2f(x * 1.44269504089f) - 1.0f;
    return x > 0.0f ? x : e;
}
#define MFMA16(a, b, c) __builtin_amdgcn_mfma_f32_16x16x32_bf16((a), (b), (c), 0, 0, 0)

// ---------------- ws layout ----------------
// All weights packed bf16, A-operand layout: pk[n*K + k] = W[k][n]
#define PK_WX0   0        // 3 x [64][32]
#define PK_WX    6144     // 6 x [64][64]
#define PK_WLX2  30720    // [16][64]   (leaked-k bug: Wlx[2] only)
#define PK_WU0   31744    // [128][64]  (k 0..31 X, 32..47 Xi, 48..63 zero)
#define PK_WU    39936    // 2 x [128][128]
#define PK_WLAST 72704    // [16][128]  (row 0 = Wlast, rest zero)
#define PK_TOTAL 74752
#define NB_PACK  292
#define WS_NEEDED ((size_t)PK_TOTAL * 2)

// wave-private swizzled LDS addressing (16B chunks XOR'd by row)
__device__ __forceinline__ short* a0_ptr(short* base, int row, int chunk) {
    return base + (row << 6) + ((chunk ^ (row & 7)) << 3);    // 16 rows x 64 shorts
}
__device__ __forceinline__ const short* a0_ptr(const short* base, int row, int chunk) {
    return base + (row << 6) + ((chunk ^ (row & 7)) << 3);
}
__device__ __forceinline__ short* u_ptr(short* base, int row, int chunk) {
    return base + (row << 7) + ((chunk ^ (row & 15)) << 3);   // 16 rows x 128 shorts
}
__device__ __forceinline__ const short* u_ptr(const short* base, int row, int chunk) {
    return base + (row << 7) + ((chunk ^ (row & 15)) << 3);
}

template<bool ACT>
__device__ __forceinline__ void epi_store(short* chunk_base, int half, float4_ a) {
    float e0, e1, e2, e3;
    if (ACT) { e0 = elu_med3(a[0]); e1 = elu_med3(a[1]); e2 = elu_med3(a[2]); e3 = elu_med3(a[3]); }
    else { e0 = a[0]; e1 = a[1]; e2 = a[2]; e3 = a[3]; }
    uint2 p; p.x = pkbf(e0, e1); p.y = pkbf(e2, e3);
    *(uint2*)(chunk_base + half * 4) = p;
}

// =====================================================================
// Kernel 1: pack fp32 weights -> bf16 A-operand layout in ws
// =====================================================================
__global__ void pack_weights(const float* __restrict__ Wx0, const float* __restrict__ Wx,
                             const float* __restrict__ Wlx, const float* __restrict__ Wu0,
                             const float* __restrict__ Wu, const float* __restrict__ Wlast,
                             short* __restrict__ pk)
{
    int idx = blockIdx.x * 256 + threadIdx.x;
    if (idx >= PK_TOTAL) return;
    float v;
    if (idx < PK_WX) {
        int m = idx / 2048, r = idx % 2048, n = r / 32, k = r % 32;
        v = Wx0[m * 2048 + k * 64 + n];
    } else if (idx < PK_WLX2) {
        int t = idx - PK_WX; int m = t / 4096, r = t % 4096, n = r / 64, k = r % 64;
        v = Wx[m * 4096 + k * 64 + n];
    } else if (idx < PK_WU0) {
        int r = idx - PK_WLX2; int n = r / 64, k = r % 64;
        v = Wlx[2 * 1024 + k * 16 + n];
    } else if (idx < PK_WU) {
        int r = idx - PK_WU0; int n = r / 64, k = r % 64;
        v = (k < 48) ? Wu0[k * 128 + n] : 0.0f;
    } else if (idx < PK_WLAST) {
        int t = idx - PK_WU; int m = t / 16384, r = t % 16384, n = r / 128, k = r % 128;
        v = Wu[m * 16384 + k * 128 + n];
    } else {
        int r = idx - PK_WLAST; int n = r / 128, k = r % 128;
        v = (n == 0) ? Wlast[k] : 0.0f;
    }
    pk[idx] = f2bf(v);
}

// =====================================================================
// Kernel 2: m-partitioned fused kernel. One customer per block.
// Wave w owns product rows w*16..w*16+15; computes ALL channels of every
// layer for its rows -> the whole MLP chain is wave-private (in-order DS,
// no barriers). Only softmax crosses waves: 1 barrier per (i,j) pass.
// LDS ~28 KB; regs ~(32 acc + 16 bf + af stream) -> fits 128 @ (256,4).
// =====================================================================
__global__ __launch_bounds__(256, 4) void rum_main(
    const float* __restrict__ X, const float* __restrict__ Z,
    const float* __restrict__ Wz0, const float* __restrict__ Wz,
    const float* __restrict__ Wlz, const float* __restrict__ Wu0,
    const short* __restrict__ pk, float* __restrict__ out)
{
    __shared__ __align__(16) short sA0[4][16 * 64];   // per-wave concat input
    __shared__ __align__(16) short sU[4][16 * 128];   // per-wave activations
    __shared__ __align__(16) float sPreZ[3 * 128];
    __shared__ float sScore[2][64];
    __shared__ float sZb[DZF];
    __shared__ float zA[3][64], zB[3][64];
    __shared__ float sZj[3][LZD];

    const int tid = threadIdx.x;
    const int w = tid >> 6, lane = tid & 63;
    const int quad = lane >> 4, l15 = lane & 15;
    const long b = blockIdx.x;
    const short8 zero8 = (short8)0;
    short* myA0 = &sA0[w][0];
    short* myU  = &sU[w][0];

    // ---- stage X (rows 0..49, chunks 0..3) + zeros (chunks 6,7; dead rows) ----
    for (int it = tid; it < 400; it += 256) {
        int r = it >> 3, c4 = it & 7;
        float4_ xv = *(const float4_*)(X + (b * 50 + r) * 32 + c4 * 4);
        uint2 p; p.x = pkbf(xv[0], xv[1]); p.y = pkbf(xv[2], xv[3]);
        *(uint2*)(a0_ptr(&sA0[r >> 4][0], r & 15, c4 >> 1) + (c4 & 1) * 4) = p;
    }
    for (int it = tid; it < 100; it += 256) {       // rows 0..49, chunks 6,7
        int r = it >> 1, ch = 6 + (it & 1);
        *(short8*)a0_ptr(&sA0[r >> 4][0], r & 15, ch) = zero8;
    }
    if (tid < 84) {                                 // rows 50..63, chunks {0..3,6,7}
        int r = 50 + tid / 6, cc = tid % 6;
        int ch = cc < 4 ? cc : cc + 2;
        *(short8*)a0_ptr(&sA0[r >> 4][0], r & 15, ch) = zero8;
    }
    if (tid < DZF) sZb[tid] = Z[b * DZF + tid];
    __syncthreads();

    // ---- inline Z-branch (wave j = w handles heterogeneity j) ----
    if (w < 3) {
        const float* wv = Wz0 + w * (DZF * 64);
        float s0 = 0.f, s1 = 0.f;
        #pragma unroll
        for (int k = 0; k < DZF; k += 2) {
            s0 = fmaf(sZb[k], wv[k * 64 + lane], s0);
            s1 = fmaf(sZb[k + 1], wv[(k + 1) * 64 + lane], s1);
        }
        zA[w][lane] = elu_fast(s0 + s1);
    }
    __syncthreads();
    if (w < 3) {
        const float* wv = Wz + (w * 2 + 0) * 4096;
        float s0 = 0.f, s1 = 0.f;
        #pragma unroll
        for (int k = 0; k < 64; k += 2) {
            s0 = fmaf(zA[w][k], wv[k * 64 + lane], s0);
            s1 = fmaf(zA[w][k + 1], wv[(k + 1) * 64 + lane], s1);
        }
        zB[w][lane] = elu_fast(s0 + s1);
    }
    __syncthreads();
    if (w < 3) {
        const float* wv = Wz + (w * 2 + 1) * 4096;
        float s0 = 0.f, s1 = 0.f;
        #pragma unroll
        for (int k = 0; k < 64; k += 2) {
            s0 = fmaf(zB[w][k], wv[k * 64 + lane], s0);
            s1 = fmaf(zB[w][k + 1], wv[(k + 1) * 64 + lane], s1);
        }
        zA[w][lane] = elu_fast(s0 + s1);
    }
    __syncthreads();
    if (w < 3 && lane < LZD) {
        const float* wv = Wlz + w * (64 * LZD);
        float s0 = 0.f, s1 = 0.f;
        #pragma unroll
        for (int k = 0; k < 64; k += 2) {
            s0 = fmaf(zA[w][k], wv[k * LZD + lane], s0);
            s1 = fmaf(zA[w][k + 1], wv[(k + 1) * LZD + lane], s1);
        }
        sZj[w][lane] = s0 + s1;
    }
    __syncthreads();
    if (w < 3) {
        #pragma unroll
        for (int half = 0; half < 2; ++half) {
            const int c = lane + half * 64;
            float s = 0.f;
            #pragma unroll
            for (int k = 0; k < LZD; ++k) s = fmaf(sZj[w][k], Wu0[(48 + k) * WUW + c], s);
            #pragma unroll
            for (int k = 0; k < DZF; ++k) s = fmaf(sZb[k], Wu0[(64 + k) * WUW + c], s);
            sPreZ[w * 128 + c] = s;
        }
    }
    __syncthreads();

    float accv = 0.f;
    const float inv_norm = 1.0f / (1.0f + 1e-6f * (float)NPROD);

    for (int i = 0; i < 3; ++i) {
        // ---- x l0: Wx0_i[64ch][32k], B from myA0 chunks 0..3 (wave-private) ----
        {
            const short* A = pk + PK_WX0 + i * 2048;
            short8 ba = *(const short8*)a0_ptr(myA0, l15, quad);
            float4_ acc0[4];
            #pragma unroll
            for (int nt = 0; nt < 4; ++nt) {
                short8 af = *(const short8*)(A + (nt * 16 + l15) * 32 + quad * 8);
                acc0[nt] = MFMA16(af, ba, (float4_)0.f);
            }
            #pragma unroll
            for (int nt = 0; nt < 4; ++nt)
                epi_store<true>(u_ptr(myU, l15, 2 * nt + (quad >> 1)), quad & 1, acc0[nt]);
        }
        // ---- x l1, l2: Wx[2i+l][64ch][64k], myU -> myU, no barrier ----
        for (int l = 0; l < 2; ++l) {
            const short* A = pk + PK_WX + (i * 2 + l) * 4096;
            short8 b0 = *(const short8*)u_ptr(myU, l15, quad);
            short8 b1 = *(const short8*)u_ptr(myU, l15, 4 + quad);
            float4_ accx[4];
            #pragma unroll
            for (int nt = 0; nt < 4; ++nt) {
                short8 af0 = *(const short8*)(A + (nt * 16 + l15) * 64 + quad * 8);
                short8 af1 = *(const short8*)(A + (nt * 16 + l15) * 64 + 32 + quad * 8);
                accx[nt] = MFMA16(af0, b0, (float4_)0.f);
                accx[nt] = MFMA16(af1, b1, accx[nt]);
            }
            #pragma unroll
            for (int nt = 0; nt < 4; ++nt)
                epi_store<true>(u_ptr(myU, l15, 2 * nt + (quad >> 1)), quad & 1, accx[nt]);
        }
        // ---- x ll: Wlx[2][16ch][64k] linear; Xi -> myA0 chunks 4,5 ----
        {
            const short* A = pk + PK_WLX2;
            short8 b0 = *(const short8*)u_ptr(myU, l15, quad);
            short8 b1 = *(const short8*)u_ptr(myU, l15, 4 + quad);
            short8 af0 = *(const short8*)(A + l15 * 64 + quad * 8);
            short8 af1 = *(const short8*)(A + l15 * 64 + 32 + quad * 8);
            float4_ a2 = MFMA16(af0, b0, (float4_)0.f);
            a2 = MFMA16(af1, b1, a2);
            epi_store<false>(a0_ptr(myA0, l15, 4 + (quad >> 1)), quad & 1, a2);
        }
        // stage u0 B-frags once per i (A0 now complete: X | Xi | 0)
        short8 ba0 = *(const short8*)a0_ptr(myA0, l15, quad);
        short8 ba1 = *(const short8*)a0_ptr(myA0, l15, 4 + quad);

        for (int j = 0; j < 3; ++j) {
            const int pass = i * 3 + j;
            // ---- u0: Wu0p[128ch][64k], C init = preZ[j] ----
            {
                const short* A = pk + PK_WU0;
                #pragma unroll
                for (int nt = 0; nt < 8; ++nt) {
                    float4_ pz = *(const float4_*)(sPreZ + j * 128 + nt * 16 + quad * 4);
                    short8 af0 = *(const short8*)(A + (nt * 16 + l15) * 64 + quad * 8);
                    short8 af1 = *(const short8*)(A + (nt * 16 + l15) * 64 + 32 + quad * 8);
                    float4_ t = MFMA16(af0, ba0, pz);
                    t = MFMA16(af1, ba1, t);
                    epi_store<true>(u_ptr(myU, l15, 2 * nt + (quad >> 1)), quad & 1, t);
                }
            }
            // ---- d1, d2: Wu[l][128ch][128k], myU -> myU ----
            for (int l = 0; l < 2; ++l) {
                const short* A = pk + PK_WU + l * 16384;
                short8 bf0 = *(const short8*)u_ptr(myU, l15, quad);
                short8 bf1 = *(const short8*)u_ptr(myU, l15, 4 + quad);
                short8 bf2 = *(const short8*)u_ptr(myU, l15, 8 + quad);
                short8 bf3 = *(const short8*)u_ptr(myU, l15, 12 + quad);
                #pragma unroll
                for (int nt = 0; nt < 8; ++nt) {
                    const short* An = A + (nt * 16 + l15) * 128 + quad * 8;
                    float4_ t = MFMA16(*(const short8*)(An), bf0, (float4_)0.f);
                    t = MFMA16(*(const short8*)(An + 32), bf1, t);
                    t = MFMA16(*(const short8*)(An + 64), bf2, t);
                    t = MFMA16(*(const short8*)(An + 96), bf3, t);
                    epi_store<true>(u_ptr(myU, l15, 2 * nt + (quad >> 1)), quad & 1, t);
                }
            }
            // ---- score: pkWlast[16][128] @ u2^T; row0 = score for m=l15 ----
            {
                const short* A = pk + PK_WLAST + l15 * 128 + quad * 8;
                short8 c0 = *(const short8*)u_ptr(myU, l15, quad);
                short8 c1 = *(const short8*)u_ptr(myU, l15, 4 + quad);
                short8 c2 = *(const short8*)u_ptr(myU, l15, 8 + quad);
                short8 c3 = *(const short8*)u_ptr(myU, l15, 12 + quad);
                float4_ t = MFMA16(*(const short8*)(A), c0, (float4_)0.f);
                t = MFMA16(*(const short8*)(A + 32), c1, t);
                t = MFMA16(*(const short8*)(A + 64), c2, t);
                t = MFMA16(*(const short8*)(A + 96), c3, t);
                if (quad == 0) sScore[pass & 1][w * 16 + l15] = t[0];
            }
            __syncthreads();   // the ONLY barrier per pass
            if (tid < 64) {
                float sc = (tid < NPROD) ? sScore[pass & 1][tid] : -3.0e38f;
                float m = sc;
                #pragma unroll
                for (int off = 32; off > 0; off >>= 1) m = fmaxf(m, __shfl_xor(m, off));
                float e = (tid < NPROD) ? __builtin_amdgcn_exp2f((sc - m) * 1.44269504089f) : 0.f;
                float ssum = e;
                #pragma unroll
                for (int off = 32; off > 0; off >>= 1) ssum += __shfl_xor(ssum, off);
                if (tid < NPROD) accv += (1e-6f + e / ssum) * inv_norm;
            }
        }
    }
    if (tid < NPROD) out[b * 50 + tid] = accv * (1.0f / 9.0f);
}

// =====================================================================
// Fallback (round-1 fp32 kernel, known-good) if ws too small
// =====================================================================
__device__ __forceinline__ float elu_f(float x) { return x > 0.0f ? x : expm1f(x); }
template<int IN, int OUT, bool ACT>
__device__ __forceinline__ void dense50(const float* __restrict__ in_lds,
                                        const float* __restrict__ Wg,
                                        float* __restrict__ out_lds)
{
    const int tid = threadIdx.x;
    constexpr int CQ = OUT / 4;
    const float4* __restrict__ W4 = (const float4*)Wg;
    for (int item = tid; item < 25 * CQ; item += 256) {
        const int rp = item / CQ, cq = item % CQ;
        const int r0 = rp, r1 = rp + 25;
        float4 a0 = {0,0,0,0}, a1 = {0,0,0,0};
        for (int k = 0; k < IN; ++k) {
            const float4 wv = W4[k * CQ + cq];
            const float x0 = in_lds[r0 * IN + k], x1 = in_lds[r1 * IN + k];
            a0.x = fmaf(x0, wv.x, a0.x); a0.y = fmaf(x0, wv.y, a0.y);
            a0.z = fmaf(x0, wv.z, a0.z); a0.w = fmaf(x0, wv.w, a0.w);
            a1.x = fmaf(x1, wv.x, a1.x); a1.y = fmaf(x1, wv.y, a1.y);
            a1.z = fmaf(x1, wv.z, a1.z); a1.w = fmaf(x1, wv.w, a1.w);
        }
        if (ACT) {
            a0.x = elu_f(a0.x); a0.y = elu_f(a0.y); a0.z = elu_f(a0.z); a0.w = elu_f(a0.w);
            a1.x = elu_f(a1.x); a1.y = elu_f(a1.y); a1.z = elu_f(a1.z); a1.w = elu_f(a1.w);
        }
        ((float4*)out_lds)[r0 * CQ + cq] = a0;
        ((float4*)out_lds)[r1 * CQ + cq] = a1;
    }
}
template<bool ACT>
__device__ __forceinline__ void dense128fb(const float* __restrict__ in_lds,
                                           const float* __restrict__ Wg,
                                           float* __restrict__ out_lds)
{
    const int tid = threadIdx.x;
    const float4* __restrict__ W4 = (const float4*)Wg;
    for (int item = tid; item < 13 * 32; item += 256) {
        const int rg = item >> 5, cq = item & 31;
        int r[4];
        #pragma unroll
        for (int t = 0; t < 4; ++t) r[t] = min(rg * 4 + t, NPROD - 1);
        float4 a[4];
        #pragma unroll
        for (int t = 0; t < 4; ++t) a[t] = make_float4(0, 0, 0, 0);
        for (int k = 0; k < 128; ++k) {
            const float4 wv = W4[k * 32 + cq];
            #pragma unroll
            for (int t = 0; t < 4; ++t) {
                const float x = in_lds[r[t] * 128 + k];
                a[t].x = fmaf(x, wv.x, a[t].x); a[t].y = fmaf(x, wv.y, a[t].y);
                a[t].z = fmaf(x, wv.z, a[t].z); a[t].w = fmaf(x, wv.w, a[t].w);
            }
        }
        #pragma unroll
        for (int t = 0; t < 4; ++t) {
            const int row = rg * 4 + t;
            if (row < NPROD) {
                float4 o = a[t];
                if (ACT) { o.x = elu_f(o.x); o.y = elu_f(o.y); o.z = elu_f(o.z); o.w = elu_f(o.w); }
                ((float4*)out_lds)[row * 32 + cq] = o;
            }
        }
    }
}
__device__ __forceinline__ void dense_u0fb(const float* __restrict__ sXb,
                                           const float* __restrict__ sXi,
                                           const float* __restrict__ preZ_j,
                                           const float* __restrict__ Wu0,
                                           float* __restrict__ out_lds)
{
    const int tid = threadIdx.x;
    const float4* __restrict__ W4 = (const float4*)Wu0;
    const float4* __restrict__ PZ4 = (const float4*)preZ_j;
    for (int item = tid; item < 13 * 32; item += 256) {
        const int rg = item >> 5, cq = item & 31;
        int r[4];
        #pragma unroll
        for (int t = 0; t < 4; ++t) r[t] = min(rg * 4 + t, NPROD - 1);
        const float4 pz = PZ4[cq];
        float4 a[4];
        #pragma unroll
        for (int t = 0; t < 4; ++t) a[t] = pz;
        for (int k = 0; k < DXF; ++k) {
            const float4 wv = W4[k * 32 + cq];
            #pragma unroll
            for (int t = 0; t < 4; ++t) {
                const float x = sXb[r[t] * DXF + k];
                a[t].x = fmaf(x, wv.x, a[t].x); a[t].y = fmaf(x, wv.y, a[t].y);
                a[t].z = fmaf(x, wv.z, a[t].z); a[t].w = fmaf(x, wv.w, a[t].w);
            }
        }
        for (int k = 0; k < LXD; ++k) {
            const float4 wv = W4[(DXF + k) * 32 + cq];
            #pragma unroll
            for (int t = 0; t < 4; ++t) {
                const float x = sXi[r[t] * LXD + k];
                a[t].x = fmaf(x, wv.x, a[t].x); a[t].y = fmaf(x, wv.y, a[t].y);
                a[t].z = fmaf(x, wv.z, a[t].z); a[t].w = fmaf(x, wv.w, a[t].w);
            }
        }
        #pragma unroll
        for (int t = 0; t < 4; ++t) {
            const int row = rg * 4 + t;
            if (row < NPROD) {
                float4 o = a[t];
                o.x = elu_f(o.x); o.y = elu_f(o.y); o.z = elu_f(o.z); o.w = elu_f(o.w);
                ((float4*)out_lds)[row * 32 + cq] = o;
            }
        }
    }
}
__global__ __launch_bounds__(256, 2) void rum_fused_fb(
    const float* __restrict__ X, const float* __restrict__ Z,
    const float* __restrict__ Wx0, const float* __restrict__ Wx,
    const float* __restrict__ Wlx, const float* __restrict__ Wz0,
    const float* __restrict__ Wz, const float* __restrict__ Wlz,
    const float* __restrict__ Wu0, const float* __restrict__ Wu,
    const float* __restrict__ Wlast, float* __restrict__ out)
{
    __shared__ __align__(16) float sBufA[NPROD * WUW];
    __shared__ __align__(16) float sBufB[NPROD * WUW];
    __shared__ __align__(16) float sXb[NPROD * DXF];
    __shared__ __align__(16) float sXi[NPROD * LXD];
    __shared__ __align__(16) float sPreZ[3 * WUW];
    const int b = blockIdx.x, tid = threadIdx.x;
    float* zsm = sBufA; float* zh0 = sBufA + 64; float* zh1 = sBufA + 256; float* zjd = sBufA + 448;
    {
        const float* Xg = X + (size_t)b * (NPROD * DXF);
        for (int idx = tid; idx < NPROD * DXF; idx += 256) sXb[idx] = Xg[idx];
        const float* Zg = Z + (size_t)b * DZF;
        if (tid < DZF) zsm[tid] = Zg[tid];
    }
    __syncthreads();
    const int zj = tid >> 6, zc = tid & 63;
    if (zj < 3) { const float* wv = Wz0 + zj * (DZF * 64); float s = 0;
        for (int k = 0; k < DZF; ++k) s = fmaf(zsm[k], wv[k * 64 + zc], s);
        zh0[zj * 64 + zc] = elu_f(s); }
    __syncthreads();
    if (zj < 3) { const float* wv = Wz + (zj * 2 + 0) * 4096; float s = 0;
        for (int k = 0; k < 64; ++k) s = fmaf(zh0[zj * 64 + k], wv[k * 64 + zc], s);
        zh1[zj * 64 + zc] = elu_f(s); }
    __syncthreads();
    if (zj < 3) { const float* wv = Wz + (zj * 2 + 1) * 4096; float s = 0;
        for (int k = 0; k < 64; ++k) s = fmaf(zh1[zj * 64 + k], wv[k * 64 + zc], s);
        zh0[zj * 64 + zc] = elu_f(s); }
    __syncthreads();
    if (tid < 48) { const int j = tid >> 4, c = tid & 15;
        const float* wv = Wlz + j * (64 * LZD); float s = 0;
        for (int k = 0; k < 64; ++k) s = fmaf(zh0[j * 64 + k], wv[k * LZD + c], s);
        zjd[j * LZD + c] = s; }
    __syncthreads();
    for (int idx = tid; idx < 3 * WUW; idx += 256) {
        const int j = idx >> 7, c = idx & 127; float s = 0;
        for (int k = 0; k < LZD; ++k) s = fmaf(zjd[j * LZD + k], Wu0[(DXF + LXD + k) * WUW + c], s);
        for (int k = 0; k < DZF; ++k) s = fmaf(zsm[k], Wu0[(DXF + LXD + LZD + k) * WUW + c], s);
        sPreZ[idx] = s;
    }
    __syncthreads();
    float accv = 0.f;
    const float inv_norm = 1.0f / (1.0f + 1e-6f * (float)NPROD);
    for (int i = 0; i < 3; ++i) {
        dense50<DXF, 64, true>(sXb, Wx0 + i * (DXF * 64), sBufA); __syncthreads();
        dense50<64, 64, true>(sBufA, Wx + (i * 2 + 0) * 4096, sBufB); __syncthreads();
        dense50<64, 64, true>(sBufB, Wx + (i * 2 + 1) * 4096, sBufA); __syncthreads();
        dense50<64, LXD, false>(sBufA, Wlx + 2 * (64 * LXD), sXi); __syncthreads();
        for (int j = 0; j < 3; ++j) {
            dense_u0fb(sXb, sXi, sPreZ + j * WUW, Wu0, sBufA); __syncthreads();
            dense128fb<true>(sBufA, Wu, sBufB); __syncthreads();
            dense128fb<true>(sBufB, Wu + 16384, sBufA); __syncthreads();
            if (tid < 64) {
                float sc = -3.0e38f;
                if (tid < NPROD) { float s = 0;
                    for (int k = 0; k < WUW; ++k) s = fmaf(sBufA[tid * WUW + k], Wlast[k], s);
                    sc = s; }
                float m = sc;
                #pragma unroll
                for (int off = 32; off > 0; off >>= 1) m = fmaxf(m, __shfl_xor(m, off));
                float e = (tid < NPROD) ? expf(sc - m) : 0.f;
                float ssum = e;
                #pragma unroll
                for (int off = 32; off > 0; off >>= 1) ssum += __shfl_xor(ssum, off);
                if (tid < NPROD) accv += (1e-6f + e / ssum) * inv_norm;
            }
            __syncthreads();
        }
    }
    if (tid < NPROD) out[(size_t)b * NPROD + tid] = accv * (1.0f / 9.0f);
}

// =====================================================================
extern "C" void kernel_launch(void* const* d_in, const int* in_sizes, int n_in,
                              void* d_out, int out_size, void* d_ws, size_t ws_size,
                              hipStream_t stream) {
    const float* X     = (const float*)d_in[0];
    const float* Z     = (const float*)d_in[1];
    const float* Wx0   = (const float*)d_in[2];
    const float* Wx    = (const float*)d_in[3];
    const float* Wlx   = (const float*)d_in[4];
    const float* Wz0   = (const float*)d_in[5];
    const float* Wz    = (const float*)d_in[6];
    const float* Wlz   = (const float*)d_in[7];
    const float* Wu0   = (const float*)d_in[8];
    const float* Wu    = (const float*)d_in[9];
    const float* Wlast = (const float*)d_in[10];
    float* out = (float*)d_out;

    if (ws_size < WS_NEEDED) {
        rum_fused_fb<<<dim3(8192), dim3(256), 0, stream>>>(
            X, Z, Wx0, Wx, Wlx, Wz0, Wz, Wlz, Wu0, Wu, Wlast, out);
        return;
    }

    short* pk = (short*)d_ws;
    pack_weights<<<dim3(NB_PACK), dim3(256), 0, stream>>>(
        Wx0, Wx, Wlx, Wu0, Wu, Wlast, pk);
    rum_main<<<dim3(8192), dim3(256), 0, stream>>>(
        X, Z, Wz0, Wz, Wlz, Wu0, pk, out);
}

// Round 7
// 837.279 us; speedup vs baseline: 3.0442x; 3.0442x over previous
//
#include <hip/hip_runtime.h>
#include <math.h>

#define NPROD 50
#define DXF 32
#define DZF 20
#define WUW 128
#define LXD 16
#define LZD 16

typedef __attribute__((ext_vector_type(8))) short short8;
typedef __attribute__((ext_vector_type(4))) float float4_;

__device__ __forceinline__ short f2bf(float x) {
    unsigned u = __builtin_bit_cast(unsigned, x);
    u += 0x7fffu + ((u >> 16) & 1u);
    return (short)(u >> 16);
}
__device__ __forceinline__ unsigned pkbf(float a, float b) {
#if __has_builtin(__builtin_amdgcn_cvt_pk_bf16_f32)
    auto v = __builtin_amdgcn_cvt_pk_bf16_f32(a, b);
    return __builtin_bit_cast(unsigned, v);
#else
    return (unsigned)(unsigned short)f2bf(a) | ((unsigned)(unsigned short)f2bf(b) << 16);
#endif
}
// elu(x) = med3(x, exp2(x*log2e)-1, 0)
__device__ __forceinline__ float elu_med3(float x) {
    float e = __builtin_amdgcn_exp2f(x * 1.44269504089f) - 1.0f;
#if __has_builtin(__builtin_amdgcn_fmed3f)
    return __builtin_amdgcn_fmed3f(x, e, 0.0f);
#else
    return x > 0.0f ? x : e;
#endif
}
__device__ __forceinline__ float elu_fast(float x) {
    float e = __builtin_amdgcn_exp2f(x * 1.44269504089f) - 1.0f;
    return x > 0.0f ? x : e;
}
#define MFMA16(a, b, c) __builtin_amdgcn_mfma_f32_16x16x32_bf16((a), (b), (c), 0, 0, 0)

// ---------------- ws layout ----------------
// All weights packed bf16, A-operand layout: pk[n*K + k] = W[k][n]
#define PK_WX0   0        // 3 x [64][32]
#define PK_WX    6144     // 6 x [64][64]
#define PK_WLX2  30720    // [16][64]   (leaked-k bug: Wlx[2] only)
#define PK_WU0   31744    // [128][64]  (k 0..31 X, 32..47 Xi, 48..63 zero)
#define PK_WU    39936    // 2 x [128][128]
#define PK_WLAST 72704    // [16][128]  (row 0 = Wlast, rest zero)
#define PK_TOTAL 74752
#define NB_PACK  292
#define WS_NEEDED ((size_t)PK_TOTAL * 2)

// swizzled LDS addressing: 16B chunks XOR'd by row (validated R4-R6: 3.4e7 confl)
__device__ __forceinline__ short* su_ptr(short* buf, int row, int chunk) {
    return buf + (row << 7) + ((chunk ^ (row & 15)) << 3);   // row stride 128 shorts
}
__device__ __forceinline__ const short* su_ptr(const short* buf, int row, int chunk) {
    return buf + (row << 7) + ((chunk ^ (row & 15)) << 3);
}
__device__ __forceinline__ short* sa_ptr(short* buf, int row, int chunk) {
    return buf + (row << 6) + ((chunk ^ (row & 7)) << 3);    // row stride 64 shorts
}
__device__ __forceinline__ const short* sa_ptr(const short* buf, int row, int chunk) {
    return buf + (row << 6) + ((chunk ^ (row & 7)) << 3);
}

template<bool ACT>
__device__ __forceinline__ void epi_store(short* chunk_base, int half, float4_ a) {
    float e0, e1, e2, e3;
    if (ACT) { e0 = elu_med3(a[0]); e1 = elu_med3(a[1]); e2 = elu_med3(a[2]); e3 = elu_med3(a[3]); }
    else { e0 = a[0]; e1 = a[1]; e2 = a[2]; e3 = a[3]; }
    uint2 p; p.x = pkbf(e0, e1); p.y = pkbf(e2, e3);
    *(uint2*)(chunk_base + half * 4) = p;
}

// =====================================================================
// Kernel 1: pack fp32 weights -> bf16 A-operand layout in ws
// =====================================================================
__global__ void pack_weights(const float* __restrict__ Wx0, const float* __restrict__ Wx,
                             const float* __restrict__ Wlx, const float* __restrict__ Wu0,
                             const float* __restrict__ Wu, const float* __restrict__ Wlast,
                             short* __restrict__ pk)
{
    int idx = blockIdx.x * 256 + threadIdx.x;
    if (idx >= PK_TOTAL) return;
    float v;
    if (idx < PK_WX) {
        int m = idx / 2048, r = idx % 2048, n = r / 32, k = r % 32;
        v = Wx0[m * 2048 + k * 64 + n];
    } else if (idx < PK_WLX2) {
        int t = idx - PK_WX; int m = t / 4096, r = t % 4096, n = r / 64, k = r % 64;
        v = Wx[m * 4096 + k * 64 + n];
    } else if (idx < PK_WU0) {
        int r = idx - PK_WLX2; int n = r / 64, k = r % 64;
        v = Wlx[2 * 1024 + k * 16 + n];
    } else if (idx < PK_WU) {
        int r = idx - PK_WU0; int n = r / 64, k = r % 64;
        v = (k < 48) ? Wu0[k * 128 + n] : 0.0f;
    } else if (idx < PK_WLAST) {
        int t = idx - PK_WU; int m = t / 16384, r = t % 16384, n = r / 128, k = r % 128;
        v = Wu[m * 16384 + k * 128 + n];
    } else {
        int r = idx - PK_WLAST; int n = r / 128, k = r % 128;
        v = (n == 0) ? Wlast[k] : 0.0f;
    }
    pk[idx] = f2bf(v);
}

// =====================================================================
// Kernel 2: n-partitioned (R3 structure) + swizzle + ping-pong + inline-Z.
// One customer per block; wave w owns channel tiles, rows shared via LDS.
// LDS ~44.8 KB -> 3 blocks/CU; launch_bounds(256,3) -> no spills (VGPR~148).
// =====================================================================
__global__ __launch_bounds__(256, 3) void rum_main(
    const float* __restrict__ X, const float* __restrict__ Z,
    const float* __restrict__ Wz0, const float* __restrict__ Wz,
    const float* __restrict__ Wlz, const float* __restrict__ Wu0,
    const short* __restrict__ pk, float* __restrict__ out)
{
    __shared__ __align__(16) short sA0[64 * 64];     // [prod][k]: X | Xi | 0
    __shared__ __align__(16) short sU0[64 * 128];    // ping
    __shared__ __align__(16) short sU1[64 * 128];    // pong
    __shared__ __align__(16) float sPreZ[3 * 128];
    __shared__ float sScore[2][64];
    __shared__ float sZb[DZF];
    __shared__ float zA[3][64], zB[3][64];
    __shared__ float sZj[3][LZD];

    const int tid = threadIdx.x;
    const int w = tid >> 6, lane = tid & 63;
    const int quad = lane >> 4, l15 = lane & 15;
    const long b = blockIdx.x;
    const short8 zero8 = (short8)0;

    // ---- stage: zeros (chunks 6,7 rows 0..49; all of rows 50..63), X rows ----
    for (int it = tid; it < 100; it += 256) {
        int r = it >> 1, ch = 6 + (it & 1);
        *(short8*)sa_ptr(sA0, r, ch) = zero8;
    }
    if (tid < 112) {
        int r = 50 + (tid >> 3), ch = tid & 7;
        *(short8*)sa_ptr(sA0, r, ch) = zero8;
    }
    for (int it = tid; it < 400; it += 256) {
        int r = it >> 3, c4 = it & 7;
        float4_ xv = *(const float4_*)(X + (b * 50 + r) * 32 + c4 * 4);
        uint2 p; p.x = pkbf(xv[0], xv[1]); p.y = pkbf(xv[2], xv[3]);
        *(uint2*)(sa_ptr(sA0, r, c4 >> 1) + (c4 & 1) * 4) = p;
    }
    if (tid < DZF) sZb[tid] = Z[b * DZF + tid];
    __syncthreads();

    // ---- inline Z-branch: wave j=w (<3) handles heterogeneity j ----
    if (w < 3) {
        const float* wv = Wz0 + w * (DZF * 64);
        float s0 = 0.f, s1 = 0.f;
        #pragma unroll
        for (int k = 0; k < DZF; k += 2) {
            s0 = fmaf(sZb[k], wv[k * 64 + lane], s0);
            s1 = fmaf(sZb[k + 1], wv[(k + 1) * 64 + lane], s1);
        }
        zA[w][lane] = elu_fast(s0 + s1);
    }
    __syncthreads();
    if (w < 3) {
        const float* wv = Wz + (w * 2 + 0) * 4096;
        float s0 = 0.f, s1 = 0.f;
        #pragma unroll
        for (int k = 0; k < 64; k += 2) {
            s0 = fmaf(zA[w][k], wv[k * 64 + lane], s0);
            s1 = fmaf(zA[w][k + 1], wv[(k + 1) * 64 + lane], s1);
        }
        zB[w][lane] = elu_fast(s0 + s1);
    }
    __syncthreads();
    if (w < 3) {
        const float* wv = Wz + (w * 2 + 1) * 4096;
        float s0 = 0.f, s1 = 0.f;
        #pragma unroll
        for (int k = 0; k < 64; k += 2) {
            s0 = fmaf(zB[w][k], wv[k * 64 + lane], s0);
            s1 = fmaf(zB[w][k + 1], wv[(k + 1) * 64 + lane], s1);
        }
        zA[w][lane] = elu_fast(s0 + s1);
    }
    __syncthreads();
    if (w < 3 && lane < LZD) {
        const float* wv = Wlz + w * (64 * LZD);
        float s0 = 0.f, s1 = 0.f;
        #pragma unroll
        for (int k = 0; k < 64; k += 2) {
            s0 = fmaf(zA[w][k], wv[k * LZD + lane], s0);
            s1 = fmaf(zA[w][k + 1], wv[(k + 1) * LZD + lane], s1);
        }
        sZj[w][lane] = s0 + s1;
    }
    __syncthreads();
    if (w < 3) {
        #pragma unroll
        for (int half = 0; half < 2; ++half) {
            const int c = lane + half * 64;
            float s = 0.f;
            #pragma unroll
            for (int k = 0; k < LZD; ++k) s = fmaf(sZj[w][k], Wu0[(48 + k) * WUW + c], s);
            #pragma unroll
            for (int k = 0; k < DZF; ++k) s = fmaf(sZb[k], Wu0[(64 + k) * WUW + c], s);
            sPreZ[w * 128 + c] = s;
        }
    }
    __syncthreads();

    float accv = 0.f;
    const float inv_norm = 1.0f / (1.0f + 1e-6f * (float)NPROD);

    for (int i = 0; i < 3; ++i) {
        // ---- x l0: Wx0_i[64][32] @ A0^T -> sU0 ----
        {
            const short* A = pk + PK_WX0 + i * 2048;
            short8 af = *(const short8*)(A + (w * 16 + l15) * 32 + quad * 8);
            #pragma unroll
            for (int pt = 0; pt < 4; ++pt) {
                short8 bfr = *(const short8*)sa_ptr(sA0, pt * 16 + l15, quad);
                float4_ acc = MFMA16(af, bfr, (float4_)0.f);
                epi_store<true>(su_ptr(sU0, pt * 16 + l15, 2 * w + (quad >> 1)), quad & 1, acc);
            }
        }
        __syncthreads();
        // ---- x l1: sU0 -> sU1; x l2: sU1 -> sU0 ----
        for (int l = 0; l < 2; ++l) {
            const short* A = pk + PK_WX + (i * 2 + l) * 4096;
            const short* sIn = l ? sU1 : sU0;
            short* sOut = l ? sU0 : sU1;
            short8 af0 = *(const short8*)(A + (w * 16 + l15) * 64 + quad * 8);
            short8 af1 = *(const short8*)(A + (w * 16 + l15) * 64 + 32 + quad * 8);
            #pragma unroll
            for (int pt = 0; pt < 4; ++pt) {
                short8 b0 = *(const short8*)su_ptr(sIn, pt * 16 + l15, quad);
                short8 b1 = *(const short8*)su_ptr(sIn, pt * 16 + l15, 4 + quad);
                float4_ acc = MFMA16(af0, b0, (float4_)0.f);
                acc = MFMA16(af1, b1, acc);
                epi_store<true>(su_ptr(sOut, pt * 16 + l15, 2 * w + (quad >> 1)), quad & 1, acc);
            }
            __syncthreads();
        }
        // ---- x ll: Wlx[2][16][64] linear, sU0 -> sA0 chunks 4,5 ----
        {
            const short* A = pk + PK_WLX2;
            short8 af0 = *(const short8*)(A + l15 * 64 + quad * 8);
            short8 af1 = *(const short8*)(A + l15 * 64 + 32 + quad * 8);
            short8 b0 = *(const short8*)su_ptr(sU0, w * 16 + l15, quad);
            short8 b1 = *(const short8*)su_ptr(sU0, w * 16 + l15, 4 + quad);
            float4_ acc = MFMA16(af0, b0, (float4_)0.f);
            acc = MFMA16(af1, b1, acc);
            epi_store<false>(sa_ptr(sA0, w * 16 + l15, 4 + (quad >> 1)), quad & 1, acc);
        }
        __syncthreads();

        for (int j = 0; j < 3; ++j) {
            const int pass = i * 3 + j;
            // ---- u0: Wu0p[128][64] @ A0^T -> sU0, C init = preZ[j] ----
            {
                const short* A = pk + PK_WU0;
                short8 b0s[4], b1s[4];
                #pragma unroll
                for (int pt = 0; pt < 4; ++pt) {
                    b0s[pt] = *(const short8*)sa_ptr(sA0, pt * 16 + l15, quad);
                    b1s[pt] = *(const short8*)sa_ptr(sA0, pt * 16 + l15, 4 + quad);
                }
                #pragma unroll
                for (int wi = 0; wi < 2; ++wi) {
                    const int wt = w * 2 + wi;
                    float4_ pz = *(const float4_*)(sPreZ + j * 128 + wt * 16 + quad * 4);
                    short8 af0 = *(const short8*)(A + (wt * 16 + l15) * 64 + quad * 8);
                    short8 af1 = *(const short8*)(A + (wt * 16 + l15) * 64 + 32 + quad * 8);
                    #pragma unroll
                    for (int pt = 0; pt < 4; ++pt) {
                        float4_ t = MFMA16(af0, b0s[pt], pz);
                        t = MFMA16(af1, b1s[pt], t);
                        epi_store<true>(su_ptr(sU0, pt * 16 + l15, 2 * wt + (quad >> 1)), quad & 1, t);
                    }
                }
            }
            __syncthreads();

            // ---- d1: sU0 -> sU1; d2: sU1 -> sU0 ----
            for (int l = 0; l < 2; ++l) {
                const short* A = pk + PK_WU + l * 16384;
                const short* sIn = l ? sU1 : sU0;
                short* sOut = l ? sU0 : sU1;
                float4_ ad[2][4];
                #pragma unroll
                for (int wi = 0; wi < 2; ++wi)
                    #pragma unroll
                    for (int pt = 0; pt < 4; ++pt) ad[wi][pt] = (float4_)0.f;
                #pragma unroll
                for (int ks = 0; ks < 4; ++ks) {
                    short8 bf[4];
                    #pragma unroll
                    for (int pt = 0; pt < 4; ++pt)
                        bf[pt] = *(const short8*)su_ptr(sIn, pt * 16 + l15, ks * 4 + quad);
                    #pragma unroll
                    for (int wi = 0; wi < 2; ++wi) {
                        short8 af = *(const short8*)(A + ((w * 2 + wi) * 16 + l15) * 128 + ks * 32 + quad * 8);
                        #pragma unroll
                        for (int pt = 0; pt < 4; ++pt)
                            ad[wi][pt] = MFMA16(af, bf[pt], ad[wi][pt]);
                    }
                }
                #pragma unroll
                for (int wi = 0; wi < 2; ++wi)
                    #pragma unroll
                    for (int pt = 0; pt < 4; ++pt)
                        epi_store<true>(su_ptr(sOut, pt * 16 + l15, 2 * (w * 2 + wi) + (quad >> 1)),
                                        quad & 1, ad[wi][pt]);
                __syncthreads();
            }

            // ---- score: pkWlast[16][128] @ u2^T (u2 in sU0); row 0 = score ----
            {
                const short* A = pk + PK_WLAST;
                float4_ as = (float4_)0.f;
                #pragma unroll
                for (int ks = 0; ks < 4; ++ks) {
                    short8 af = *(const short8*)(A + l15 * 128 + ks * 32 + quad * 8);
                    short8 bf = *(const short8*)su_ptr(sU0, w * 16 + l15, ks * 4 + quad);
                    as = MFMA16(af, bf, as);
                }
                if (quad == 0) sScore[pass & 1][w * 16 + l15] = as[0];
            }
            __syncthreads();
            // ---- softmax (wave 0); no trailing barrier (sScore double-buffered) ----
            if (tid < 64) {
                float sc = (tid < NPROD) ? sScore[pass & 1][tid] : -3.0e38f;
                float m = sc;
                #pragma unroll
                for (int off = 32; off > 0; off >>= 1) m = fmaxf(m, __shfl_xor(m, off));
                float e = (tid < NPROD) ? __builtin_amdgcn_exp2f((sc - m) * 1.44269504089f) : 0.f;
                float ssum = e;
                #pragma unroll
                for (int off = 32; off > 0; off >>= 1) ssum += __shfl_xor(ssum, off);
                if (tid < NPROD) accv += (1e-6f + e / ssum) * inv_norm;
            }
        }
    }
    if (tid < NPROD) out[b * 50 + tid] = accv * (1.0f / 9.0f);
}

// =====================================================================
// Fallback (round-1 fp32 kernel, known-good) if ws too small
// =====================================================================
__device__ __forceinline__ float elu_f(float x) { return x > 0.0f ? x : expm1f(x); }
template<int IN, int OUT, bool ACT>
__device__ __forceinline__ void dense50(const float* __restrict__ in_lds,
                                        const float* __restrict__ Wg,
                                        float* __restrict__ out_lds)
{
    const int tid = threadIdx.x;
    constexpr int CQ = OUT / 4;
    const float4* __restrict__ W4 = (const float4*)Wg;
    for (int item = tid; item < 25 * CQ; item += 256) {
        const int rp = item / CQ, cq = item % CQ;
        const int r0 = rp, r1 = rp + 25;
        float4 a0 = {0,0,0,0}, a1 = {0,0,0,0};
        for (int k = 0; k < IN; ++k) {
            const float4 wv = W4[k * CQ + cq];
            const float x0 = in_lds[r0 * IN + k], x1 = in_lds[r1 * IN + k];
            a0.x = fmaf(x0, wv.x, a0.x); a0.y = fmaf(x0, wv.y, a0.y);
            a0.z = fmaf(x0, wv.z, a0.z); a0.w = fmaf(x0, wv.w, a0.w);
            a1.x = fmaf(x1, wv.x, a1.x); a1.y = fmaf(x1, wv.y, a1.y);
            a1.z = fmaf(x1, wv.z, a1.z); a1.w = fmaf(x1, wv.w, a1.w);
        }
        if (ACT) {
            a0.x = elu_f(a0.x); a0.y = elu_f(a0.y); a0.z = elu_f(a0.z); a0.w = elu_f(a0.w);
            a1.x = elu_f(a1.x); a1.y = elu_f(a1.y); a1.z = elu_f(a1.z); a1.w = elu_f(a1.w);
        }
        ((float4*)out_lds)[r0 * CQ + cq] = a0;
        ((float4*)out_lds)[r1 * CQ + cq] = a1;
    }
}
template<bool ACT>
__device__ __forceinline__ void dense128fb(const float* __restrict__ in_lds,
                                           const float* __restrict__ Wg,
                                           float* __restrict__ out_lds)
{
    const int tid = threadIdx.x;
    const float4* __restrict__ W4 = (const float4*)Wg;
    for (int item = tid; item < 13 * 32; item += 256) {
        const int rg = item >> 5, cq = item & 31;
        int r[4];
        #pragma unroll
        for (int t = 0; t < 4; ++t) r[t] = min(rg * 4 + t, NPROD - 1);
        float4 a[4];
        #pragma unroll
        for (int t = 0; t < 4; ++t) a[t] = make_float4(0, 0, 0, 0);
        for (int k = 0; k < 128; ++k) {
            const float4 wv = W4[k * 32 + cq];
            #pragma unroll
            for (int t = 0; t < 4; ++t) {
                const float x = in_lds[r[t] * 128 + k];
                a[t].x = fmaf(x, wv.x, a[t].x); a[t].y = fmaf(x, wv.y, a[t].y);
                a[t].z = fmaf(x, wv.z, a[t].z); a[t].w = fmaf(x, wv.w, a[t].w);
            }
        }
        #pragma unroll
        for (int t = 0; t < 4; ++t) {
            const int row = rg * 4 + t;
            if (row < NPROD) {
                float4 o = a[t];
                if (ACT) { o.x = elu_f(o.x); o.y = elu_f(o.y); o.z = elu_f(o.z); o.w = elu_f(o.w); }
                ((float4*)out_lds)[row * 32 + cq] = o;
            }
        }
    }
}
__device__ __forceinline__ void dense_u0fb(const float* __restrict__ sXb,
                                           const float* __restrict__ sXi,
                                           const float* __restrict__ preZ_j,
                                           const float* __restrict__ Wu0,
                                           float* __restrict__ out_lds)
{
    const int tid = threadIdx.x;
    const float4* __restrict__ W4 = (const float4*)Wu0;
    const float4* __restrict__ PZ4 = (const float4*)preZ_j;
    for (int item = tid; item < 13 * 32; item += 256) {
        const int rg = item >> 5, cq = item & 31;
        int r[4];
        #pragma unroll
        for (int t = 0; t < 4; ++t) r[t] = min(rg * 4 + t, NPROD - 1);
        const float4 pz = PZ4[cq];
        float4 a[4];
        #pragma unroll
        for (int t = 0; t < 4; ++t) a[t] = pz;
        for (int k = 0; k < DXF; ++k) {
            const float4 wv = W4[k * 32 + cq];
            #pragma unroll
            for (int t = 0; t < 4; ++t) {
                const float x = sXb[r[t] * DXF + k];
                a[t].x = fmaf(x, wv.x, a[t].x); a[t].y = fmaf(x, wv.y, a[t].y);
                a[t].z = fmaf(x, wv.z, a[t].z); a[t].w = fmaf(x, wv.w, a[t].w);
            }
        }
        for (int k = 0; k < LXD; ++k) {
            const float4 wv = W4[(DXF + k) * 32 + cq];
            #pragma unroll
            for (int t = 0; t < 4; ++t) {
                const float x = sXi[r[t] * LXD + k];
                a[t].x = fmaf(x, wv.x, a[t].x); a[t].y = fmaf(x, wv.y, a[t].y);
                a[t].z = fmaf(x, wv.z, a[t].z); a[t].w = fmaf(x, wv.w, a[t].w);
            }
        }
        #pragma unroll
        for (int t = 0; t < 4; ++t) {
            const int row = rg * 4 + t;
            if (row < NPROD) {
                float4 o = a[t];
                o.x = elu_f(o.x); o.y = elu_f(o.y); o.z = elu_f(o.z); o.w = elu_f(o.w);
                ((float4*)out_lds)[row * 32 + cq] = o;
            }
        }
    }
}
__global__ __launch_bounds__(256, 2) void rum_fused_fb(
    const float* __restrict__ X, const float* __restrict__ Z,
    const float* __restrict__ Wx0, const float* __restrict__ Wx,
    const float* __restrict__ Wlx, const float* __restrict__ Wz0,
    const float* __restrict__ Wz, const float* __restrict__ Wlz,
    const float* __restrict__ Wu0, const float* __restrict__ Wu,
    const float* __restrict__ Wlast, float* __restrict__ out)
{
    __shared__ __align__(16) float sBufA[NPROD * WUW];
    __shared__ __align__(16) float sBufB[NPROD * WUW];
    __shared__ __align__(16) float sXb[NPROD * DXF];
    __shared__ __align__(16) float sXi[NPROD * LXD];
    __shared__ __align__(16) float sPreZ[3 * WUW];
    const int b = blockIdx.x, tid = threadIdx.x;
    float* zsm = sBufA; float* zh0 = sBufA + 64; float* zh1 = sBufA + 256; float* zjd = sBufA + 448;
    {
        const float* Xg = X + (size_t)b * (NPROD * DXF);
        for (int idx = tid; idx < NPROD * DXF; idx += 256) sXb[idx] = Xg[idx];
        const float* Zg = Z + (size_t)b * DZF;
        if (tid < DZF) zsm[tid] = Zg[tid];
    }
    __syncthreads();
    const int zj = tid >> 6, zc = tid & 63;
    if (zj < 3) { const float* wv = Wz0 + zj * (DZF * 64); float s = 0;
        for (int k = 0; k < DZF; ++k) s = fmaf(zsm[k], wv[k * 64 + zc], s);
        zh0[zj * 64 + zc] = elu_f(s); }
    __syncthreads();
    if (zj < 3) { const float* wv = Wz + (zj * 2 + 0) * 4096; float s = 0;
        for (int k = 0; k < 64; ++k) s = fmaf(zh0[zj * 64 + k], wv[k * 64 + zc], s);
        zh1[zj * 64 + zc] = elu_f(s); }
    __syncthreads();
    if (zj < 3) { const float* wv = Wz + (zj * 2 + 1) * 4096; float s = 0;
        for (int k = 0; k < 64; ++k) s = fmaf(zh1[zj * 64 + k], wv[k * 64 + zc], s);
        zh0[zj * 64 + zc] = elu_f(s); }
    __syncthreads();
    if (tid < 48) { const int j = tid >> 4, c = tid & 15;
        const float* wv = Wlz + j * (64 * LZD); float s = 0;
        for (int k = 0; k < 64; ++k) s = fmaf(zh0[j * 64 + k], wv[k * LZD + c], s);
        zjd[j * LZD + c] = s; }
    __syncthreads();
    for (int idx = tid; idx < 3 * WUW; idx += 256) {
        const int j = idx >> 7, c = idx & 127; float s = 0;
        for (int k = 0; k < LZD; ++k) s = fmaf(zjd[j * LZD + k], Wu0[(DXF + LXD + k) * WUW + c], s);
        for (int k = 0; k < DZF; ++k) s = fmaf(zsm[k], Wu0[(DXF + LXD + LZD + k) * WUW + c], s);
        sPreZ[idx] = s;
    }
    __syncthreads();
    float accv = 0.f;
    const float inv_norm = 1.0f / (1.0f + 1e-6f * (float)NPROD);
    for (int i = 0; i < 3; ++i) {
        dense50<DXF, 64, true>(sXb, Wx0 + i * (DXF * 64), sBufA); __syncthreads();
        dense50<64, 64, true>(sBufA, Wx + (i * 2 + 0) * 4096, sBufB); __syncthreads();
        dense50<64, 64, true>(sBufB, Wx + (i * 2 + 1) * 4096, sBufA); __syncthreads();
        dense50<64, LXD, false>(sBufA, Wlx + 2 * (64 * LXD), sXi); __syncthreads();
        for (int j = 0; j < 3; ++j) {
            dense_u0fb(sXb, sXi, sPreZ + j * WUW, Wu0, sBufA); __syncthreads();
            dense128fb<true>(sBufA, Wu, sBufB); __syncthreads();
            dense128fb<true>(sBufB, Wu + 16384, sBufA); __syncthreads();
            if (tid < 64) {
                float sc = -3.0e38f;
                if (tid < NPROD) { float s = 0;
                    for (int k = 0; k < WUW; ++k) s = fmaf(sBufA[tid * WUW + k], Wlast[k], s);
                    sc = s; }
                float m = sc;
                #pragma unroll
                for (int off = 32; off > 0; off >>= 1) m = fmaxf(m, __shfl_xor(m, off));
                float e = (tid < NPROD) ? expf(sc - m) : 0.f;
                float ssum = e;
                #pragma unroll
                for (int off = 32; off > 0; off >>= 1) ssum += __shfl_xor(ssum, off);
                if (tid < NPROD) accv += (1e-6f + e / ssum) * inv_norm;
            }
            __syncthreads();
        }
    }
    if (tid < NPROD) out[(size_t)b * NPROD + tid] = accv * (1.0f / 9.0f);
}

// =====================================================================
extern "C" void kernel_launch(void* const* d_in, const int* in_sizes, int n_in,
                              void* d_out, int out_size, void* d_ws, size_t ws_size,
                              hipStream_t stream) {
    const float* X     = (const float*)d_in[0];
    const float* Z     = (const float*)d_in[1];
    const float* Wx0   = (const float*)d_in[2];
    const float* Wx    = (const float*)d_in[3];
    const float* Wlx   = (const float*)d_in[4];
    const float* Wz0   = (const float*)d_in[5];
    const float* Wz    = (const float*)d_in[6];
    const float* Wlz   = (const float*)d_in[7];
    const float* Wu0   = (const float*)d_in[8];
    const float* Wu    = (const float*)d_in[9];
    const float* Wlast = (const float*)d_in[10];
    float* out = (float*)d_out;

    if (ws_size < WS_NEEDED) {
        rum_fused_fb<<<dim3(8192), dim3(256), 0, stream>>>(
            X, Z, Wx0, Wx, Wlx, Wz0, Wz, Wlz, Wu0, Wu, Wlast, out);
        return;
    }

    short* pk = (short*)d_ws;
    pack_weights<<<dim3(NB_PACK), dim3(256), 0, stream>>>(
        Wx0, Wx, Wlx, Wu0, Wu, Wlast, pk);
    rum_main<<<dim3(8192), dim3(256), 0, stream>>>(
        X, Z, Wz0, Wz, Wlz, Wu0, pk, out);
}